// Round 12
// baseline (110.414 us; speedup 1.0000x reference)
//
#include <hip/hip_runtime.h>

// Problem constants (B=1)
#define NQ   512
#define NKV  2562
#define CH   64
#define QB   2           // queries per attn block
#define BT   256         // attn block threads (4 waves); grid 1024 -> 4 blocks/CU
#define NJQ  4           // j-range split
#define JQ   641         // ceil(NKV/4)
#define PSTRIDE 132      // per (qpair, quarter): s0,s1,pad,pad, o0[64], o1[64]
#define LOG2E 1.44269504088896340736f
#define KROW 192         // kvp row: EK[64] | EKi[64] | v[64]

// gemm grid partition
#define KVROWS 8
#define NKVB ((NKV + KVROWS - 1) / KVROWS)   // 321
#define QROWS 16
#define NQB (NQ / QROWS)                     // 32
#define NCB  81                              // ceil(NKV*8/256) for kvc8 table

// raw 1-instruction exp2 (OCML exp2f adds range-fixup; v_exp_f32 IS 2^x)
static __device__ __forceinline__ float exp2_raw(float x) {
  float r; asm("v_exp_f32 %0, %1" : "=v"(r) : "v"(x)); return r;
}
// exp(-|a-b|) = min(e^a * e^-b, e^-a * e^b); EQ=e^a, EQi=e^-a, EK=e^b, EKi=e^-b
#define TMIN(EQ, EQi, EK, EKi) fminf((EQ) * (EKi), (EQi) * (EK))

// ---------------------------------------------------------------------------
// Kernel A: qp[i] = {e^{q_}, e^{-q_}} (128 f);
//           kvp[j] = {e^{k}, e^{-k}, v} (192 f);
//           kvc8[j] = {e^{kc}, pad, e^{-kc}, pad} (8 f).
// ---------------------------------------------------------------------------
__global__ __launch_bounds__(256) void gemm_qkv(
    const float* __restrict__ q, const float* __restrict__ kv,
    const float* __restrict__ Wq, const float* __restrict__ Wkv,
    const float* __restrict__ kvc, float* __restrict__ qp,
    float* __restrict__ kvp, float* __restrict__ kvc8) {
  const int tid = threadIdx.x;
  if (blockIdx.x < NKVB) {
    const int j0 = blockIdx.x * KVROWS;
    __shared__ float s_in[KVROWS][CH];
    if (tid < KVROWS * (CH / 4)) {
      int r = tid >> 4, g = tid & 15;
      int j = j0 + r;
      float4 v = (j < NKV) ? ((const float4*)(kv + (size_t)j * CH))[g]
                           : make_float4(0.f, 0.f, 0.f, 0.f);
      ((float4*)&s_in[r][0])[g] = v;
    }
    __syncthreads();
    const int r = tid >> 5;
    const int mg = (tid & 31) * 4;      // 0..124, covers 128 cols of kv_
    float4 acc = make_float4(0.f, 0.f, 0.f, 0.f);
#pragma unroll 16
    for (int rr = 0; rr < CH; ++rr) {
      float a = s_in[r][rr];
      float4 w = *(const float4*)(Wkv + (size_t)rr * 2 * CH + mg);
      acc.x = fmaf(a, w.x, acc.x); acc.y = fmaf(a, w.y, acc.y);
      acc.z = fmaf(a, w.z, acc.z); acc.w = fmaf(a, w.w, acc.w);
    }
    int j = j0 + r;
    if (j < NKV) {
      if (mg < CH) {   // k columns: store EK and EKi
        float4 ek, eki;
        ek.x = exp2_raw(acc.x * LOG2E);  eki.x = exp2_raw(-acc.x * LOG2E);
        ek.y = exp2_raw(acc.y * LOG2E);  eki.y = exp2_raw(-acc.y * LOG2E);
        ek.z = exp2_raw(acc.z * LOG2E);  eki.z = exp2_raw(-acc.z * LOG2E);
        ek.w = exp2_raw(acc.w * LOG2E);  eki.w = exp2_raw(-acc.w * LOG2E);
        *(float4*)(kvp + (size_t)j * KROW + mg) = ek;
        *(float4*)(kvp + (size_t)j * KROW + 64 + mg) = eki;
      } else {         // v columns: raw, at 128+(mg-64) == 64+mg
        *(float4*)(kvp + (size_t)j * KROW + 64 + mg) = acc;
      }
    }
  } else if (blockIdx.x < NKVB + NQB) {
    const int i0 = (blockIdx.x - NKVB) * QROWS;
    __shared__ float s_in[QROWS][CH];
    {
      int r = tid >> 4, g = tid & 15;
      float4 v = ((const float4*)(q + (size_t)(i0 + r) * CH))[g];
      ((float4*)&s_in[r][0])[g] = v;
    }
    __syncthreads();
    const int r = tid >> 4;
    const int cg = (tid & 15) * 4;
    float4 acc = make_float4(0.f, 0.f, 0.f, 0.f);
#pragma unroll 16
    for (int rr = 0; rr < CH; ++rr) {
      float a = s_in[r][rr];
      float4 w = *(const float4*)(Wq + (size_t)rr * CH + cg);
      acc.x = fmaf(a, w.x, acc.x); acc.y = fmaf(a, w.y, acc.y);
      acc.z = fmaf(a, w.z, acc.z); acc.w = fmaf(a, w.w, acc.w);
    }
    float4 eq, eqi;
    eq.x = exp2_raw(acc.x * LOG2E);  eqi.x = exp2_raw(-acc.x * LOG2E);
    eq.y = exp2_raw(acc.y * LOG2E);  eqi.y = exp2_raw(-acc.y * LOG2E);
    eq.z = exp2_raw(acc.z * LOG2E);  eqi.z = exp2_raw(-acc.z * LOG2E);
    eq.w = exp2_raw(acc.w * LOG2E);  eqi.w = exp2_raw(-acc.w * LOG2E);
    *(float4*)(qp + (size_t)(i0 + r) * 128 + cg) = eq;
    *(float4*)(qp + (size_t)(i0 + r) * 128 + 64 + cg) = eqi;
  } else {
    // kvc8: {e^{kc0..2}, pad, e^{-kc0..2}, pad}
    int t = (blockIdx.x - NKVB - NQB) * 256 + tid;
    if (t < NKV * 8) {
      int j = t >> 3, d = t & 7;
      float val = 0.f;
      if (d < 3)               val = exp2_raw( kvc[(size_t)j * 3 + d]      * LOG2E);
      else if (d >= 4 && d < 7) val = exp2_raw(-kvc[(size_t)j * 3 + (d-4)] * LOG2E);
      kvc8[t] = val;
    }
  }
}

// ---------------------------------------------------------------------------
// Kernel B1: partial attention over a j-quarter for 2 queries.
// 8-way channel split: lane sub = tid&7 owns channels [8*sub, +8).
// Hot loop is pure full-rate VALU: term = min(EQ*EKi, EQi*EK) (no trans).
// Single-pass (scores bounded; no max subtraction).
// ---------------------------------------------------------------------------
__global__ __launch_bounds__(BT, 4) void attn_part(
    const float* __restrict__ qp, const float* __restrict__ kvp,
    const float* __restrict__ qc, const float* __restrict__ kvc8,
    const float* __restrict__ Wdelta, float* __restrict__ part) {
  __shared__ float s_score[QB][JQ];    // 5128 B
  __shared__ float s_red[QB][BT];      // 2048 B
  __shared__ float s_wd[3];

  const int qpair = blockIdx.x >> 2;
  const int h = blockIdx.x & 3;
  const int i0 = qpair * QB;
  const int jlo = h * JQ;
  const int jhi = (jlo + JQ < NKV) ? jlo + JQ : NKV;

  const int tid = threadIdx.x;
  const int sub = tid & 7;
  const int c0 = sub * 8;
  const int wid = tid >> 6;
  const int lane = tid & 63;

  if (tid < 3) {
    float s = 0.f;
    for (int c = 0; c < CH; ++c) s += Wdelta[tid * CH + c];
    s_wd[tid] = s;
  }

  // q exp slices into named registers: EQ/EQi for 2 queries x 8 channels
  const float4* pa  = (const float4*)(qp + (size_t)(i0 + 0) * 128 + c0);
  const float4* pai = (const float4*)(qp + (size_t)(i0 + 0) * 128 + 64 + c0);
  const float4* pb  = (const float4*)(qp + (size_t)(i0 + 1) * 128 + c0);
  const float4* pbi = (const float4*)(qp + (size_t)(i0 + 1) * 128 + 64 + c0);
  float4 qa0 = pa[0],  qa1 = pa[1];
  float4 qA0 = pai[0], qA1 = pai[1];
  float4 qb0 = pb[0],  qb1 = pb[1];
  float4 qB0 = pbi[0], qB1 = pbi[1];
  asm volatile("" : "+v"(qa0.x), "+v"(qa0.y), "+v"(qa0.z), "+v"(qa0.w),
                    "+v"(qa1.x), "+v"(qa1.y), "+v"(qa1.z), "+v"(qa1.w),
                    "+v"(qA0.x), "+v"(qA0.y), "+v"(qA0.z), "+v"(qA0.w),
                    "+v"(qA1.x), "+v"(qA1.y), "+v"(qA1.z), "+v"(qA1.w));
  asm volatile("" : "+v"(qb0.x), "+v"(qb0.y), "+v"(qb0.z), "+v"(qb0.w),
                    "+v"(qb1.x), "+v"(qb1.y), "+v"(qb1.z), "+v"(qb1.w),
                    "+v"(qB0.x), "+v"(qB0.y), "+v"(qB0.z), "+v"(qB0.w),
                    "+v"(qB1.x), "+v"(qB1.y), "+v"(qB1.z), "+v"(qB1.w));

  // q coord exps (e^{qc}, e^{-qc}) for both queries
  float ca[3], cA[3], cb[3], cB[3];
#pragma unroll
  for (int d = 0; d < 3; ++d) {
    float v0 = qc[(size_t)(i0 + 0) * 3 + d] * LOG2E;
    float v1 = qc[(size_t)(i0 + 1) * 3 + d] * LOG2E;
    ca[d] = exp2_raw(v0);  cA[d] = exp2_raw(-v0);
    cb[d] = exp2_raw(v1);  cB[d] = exp2_raw(-v1);
  }
  __syncthreads();
  const float wd0 = s_wd[0], wd1 = s_wd[1], wd2 = s_wd[2];
  const float pscale = (1.0f / 64.0f) * LOG2E;   // p = 2^(score * pscale)

  // ---- phase 1: scores via min-product, fused running sums ----
  float ls0 = 0.f, ls1 = 0.f;
  for (int j = jlo + (tid >> 3); j < jhi; j += BT / 8) {
    const float4* ek  = (const float4*)(kvp + (size_t)j * KROW + c0);
    const float4* eki = (const float4*)(kvp + (size_t)j * KROW + 64 + c0);
    float4 k0 = ek[0], k1 = ek[1];
    float4 K0 = eki[0], K1 = eki[1];

    float s0 = ((TMIN(qa0.x, qA0.x, k0.x, K0.x) + TMIN(qa0.y, qA0.y, k0.y, K0.y))
             +  (TMIN(qa0.z, qA0.z, k0.z, K0.z) + TMIN(qa0.w, qA0.w, k0.w, K0.w)))
             + ((TMIN(qa1.x, qA1.x, k1.x, K1.x) + TMIN(qa1.y, qA1.y, k1.y, K1.y))
             +  (TMIN(qa1.z, qA1.z, k1.z, K1.z) + TMIN(qa1.w, qA1.w, k1.w, K1.w)));
    float s1 = ((TMIN(qb0.x, qB0.x, k0.x, K0.x) + TMIN(qb0.y, qB0.y, k0.y, K0.y))
             +  (TMIN(qb0.z, qB0.z, k0.z, K0.z) + TMIN(qb0.w, qB0.w, k0.w, K0.w)))
             + ((TMIN(qb1.x, qB1.x, k1.x, K1.x) + TMIN(qb1.y, qB1.y, k1.y, K1.y))
             +  (TMIN(qb1.z, qB1.z, k1.z, K1.z) + TMIN(qb1.w, qB1.w, k1.w, K1.w)));
    // reduce across the 8-lane channel group
    s0 += __shfl_xor(s0, 1); s0 += __shfl_xor(s0, 2); s0 += __shfl_xor(s0, 4);
    s1 += __shfl_xor(s1, 1); s1 += __shfl_xor(s1, 2); s1 += __shfl_xor(s1, 4);
    if (sub == 0) {
      float4 kc  = *(const float4*)(kvc8 + (size_t)j * 8);      // e^{kc}
      float4 kci = *(const float4*)(kvc8 + (size_t)j * 8 + 4);  // e^{-kc}
      s0 += TMIN(ca[0], cA[0], kc.x, kci.x) * wd0
          + TMIN(ca[1], cA[1], kc.y, kci.y) * wd1
          + TMIN(ca[2], cA[2], kc.z, kci.z) * wd2;
      s1 += TMIN(cb[0], cB[0], kc.x, kci.x) * wd0
          + TMIN(cb[1], cB[1], kc.y, kci.y) * wd1
          + TMIN(cb[2], cB[2], kc.z, kci.z) * wd2;
      float p0 = exp2_raw(s0 * pscale);
      float p1 = exp2_raw(s1 * pscale);
      int jj = j - jlo;
      s_score[0][jj] = p0; s_score[1][jj] = p1;
      ls0 += p0; ls1 += p1;
    }
  }

  // ---- sums: wave shfl reduce + cross-wave combine ----
#pragma unroll
  for (int off = 8; off < 64; off <<= 1) {   // sub-groups already reduced to sub==0
    ls0 += __shfl_xor(ls0, off);
    ls1 += __shfl_xor(ls1, off);
  }
  // lanes with sub!=0 hold 0 contributions; xor 1,2,4 add them harmlessly
  ls0 += __shfl_xor(ls0, 1); ls0 += __shfl_xor(ls0, 2); ls0 += __shfl_xor(ls0, 4);
  ls1 += __shfl_xor(ls1, 1); ls1 += __shfl_xor(ls1, 2); ls1 += __shfl_xor(ls1, 4);
  if (lane == 0) { s_red[0][wid] = ls0; s_red[1][wid] = ls1; }
  __syncthreads();
  float t0 = s_red[0][0], t1 = s_red[1][0];
#pragma unroll
  for (int w = 1; w < BT / 64; ++w) { t0 += s_red[0][w]; t1 += s_red[1][w]; }
  __syncthreads();   // done reading s_red before reuse; s_score visible

  // ---- phase 2: unnormalized o[c] = sum_j p_j * v[j,c], 4 j-groups ----
  const int c = tid & 63, g = tid >> 6;   // g in [0,4)
  float a0 = 0.f, a1 = 0.f;
#pragma unroll 8
  for (int j2 = jlo + g; j2 < jhi; j2 += 4) {
    float v = kvp[(size_t)j2 * KROW + 128 + c];
    int jj = j2 - jlo;
    a0 = fmaf(s_score[0][jj], v, a0);
    a1 = fmaf(s_score[1][jj], v, a1);
  }
  s_red[0][tid] = a0; s_red[1][tid] = a1;
  __syncthreads();

  float* P = part + (size_t)(qpair * NJQ + h) * PSTRIDE;
  if (g == 0) {
    float u0 = 0.f, u1 = 0.f;
#pragma unroll
    for (int gg = 0; gg < 4; ++gg) {
      u0 += s_red[0][gg * 64 + c];
      u1 += s_red[1][gg * 64 + c];
    }
    P[4 + c] = u0;
    P[68 + c] = u1;
    if (c == 0) { P[0] = t0; P[1] = t1; }
  }
}

// ---------------------------------------------------------------------------
// Kernel B2: merge quarters + projection. Block = 4 queries x 64 channels.
// ---------------------------------------------------------------------------
__global__ __launch_bounds__(256) void attn_merge(
    const float* __restrict__ part, const float* __restrict__ Wproj,
    const float* __restrict__ bproj, float* __restrict__ out) {
  __shared__ float s_o[4][CH];
  const int tid = threadIdx.x;
  const int g = tid >> 6, c = tid & 63;
  const int i = blockIdx.x * 4 + g;
  const int qpi = i >> 1, qs = i & 1;

  float ssum = 0.f, osum = 0.f;
#pragma unroll
  for (int h = 0; h < NJQ; ++h) {
    const float* P = part + (size_t)(qpi * NJQ + h) * PSTRIDE;
    ssum += P[qs];
    osum += P[4 + qs * 64 + c];
  }
  s_o[g][c] = osum / ssum;
  __syncthreads();

  float acc = 0.f;
#pragma unroll 16
  for (int r = 0; r < CH; ++r)
    acc = fmaf(s_o[g][r], Wproj[r * CH + c], acc);
  out[(size_t)i * CH + c] = acc + bproj[c];
}

// ---------------------------------------------------------------------------
extern "C" void kernel_launch(void* const* d_in, const int* in_sizes, int n_in,
                              void* d_out, int out_size, void* d_ws, size_t ws_size,
                              hipStream_t stream) {
  const float* q      = (const float*)d_in[0];
  const float* qc     = (const float*)d_in[1];
  const float* kv     = (const float*)d_in[2];
  const float* kvc    = (const float*)d_in[3];
  const float* Wq     = (const float*)d_in[4];
  const float* Wkv    = (const float*)d_in[5];
  const float* Wdelta = (const float*)d_in[6];
  const float* Wproj  = (const float*)d_in[7];
  const float* bproj  = (const float*)d_in[8];
  float* outp = (float*)d_out;

  float* qp   = (float*)d_ws;                              // 512*128
  float* kvp  = qp + (size_t)NQ * 128;                     // 2562*192
  float* part = kvp + (size_t)NKV * KROW;                  // 256*4*132
  float* kvc8 = part + (size_t)(NQ / QB) * NJQ * PSTRIDE;  // 2562*8

  gemm_qkv<<<NKVB + NQB + NCB, 256, 0, stream>>>(q, kv, Wq, Wkv, kvc, qp, kvp, kvc8);
  attn_part<<<(NQ / QB) * NJQ, BT, 0, stream>>>(qp, kvp, qc, kvc8, Wdelta, part);
  attn_merge<<<NQ / 4, 256, 0, stream>>>(part, Wproj, bproj, outp);
}